// Round 2
// baseline (979.487 us; speedup 1.0000x reference)
//
#include <hip/hip_runtime.h>
#include <math.h>

#define T_TOKENS 8192
#define NEXP 64
#define HID 2048
#define NITER 30
#define SINK_BLOCKS 32

// ws/comm layout (floats): [0,1920) colsum[iter][e]; int cnt[iter] at float-index 1984..2013
#define CNT_OFF 1984

// ---------------------------------------------------------------------------
// Kernel 1: router GEMM. 512 blocks x 128 threads (2 waves).
// Block: 16 tokens x 64 experts x K=2048. lane = expert; 8 tokens/thread.
// A is read from GLOBAL as wave-uniform float4 broadcasts (VMEM pipe, L1-hot),
// W staged in LDS (XOR-swizzled, double-buffered). DS pipe ~= VALU ~= 33k cyc/CU.
// ---------------------------------------------------------------------------
__global__ __launch_bounds__(128)
void gemm_router_v2(const float* __restrict__ A, const float* __restrict__ W,
                    float* __restrict__ out, float* __restrict__ comm)
{
    __shared__ float Bs[2][64 * 64];
    const int tid  = threadIdx.x;
    const int bid  = blockIdx.x;
    const int e    = tid & 63;
    const int wv   = tid >> 6;
    const int tok0 = bid * 16 + wv * 8;

    // zero the sinkhorn comm area (colsums + counters); done before sinkhorn launch
    if (bid == 0) {
        for (int i = tid; i < 2048 + 64; i += 128) comm[i] = 0.0f;
    }

    float acc[8] = {0.f, 0.f, 0.f, 0.f, 0.f, 0.f, 0.f, 0.f};

    // stage W chunk 0 (64 experts x 64 k), swizzled: slot = k4 ^ (e & 15)
#pragma unroll
    for (int i = 0; i < 8; i++) {
        int f = i * 128 + tid; int es = f >> 4, k4 = f & 15;
        float4 v = *(const float4*)(W + (size_t)es * HID + k4 * 4);
        *(float4*)(&Bs[0][es * 64 + ((k4 ^ (es & 15)) << 2)]) = v;
    }
    __syncthreads();

    const float* Arow = A + (size_t)tok0 * HID;

    for (int c = 0; c < 32; ++c) {
        const int buf = c & 1;
        const int kb  = c * 64;

        float4 wpre[8];
        if (c < 31) {
#pragma unroll
            for (int i = 0; i < 8; i++) {
                int f = i * 128 + tid; int es = f >> 4, k4 = f & 15;
                wpre[i] = *(const float4*)(W + (size_t)es * HID + kb + 64 + k4 * 4);
            }
        }

        // A: 1-deep software pipeline of wave-uniform global float4 loads
        float4 acur[8], anxt[8];
#pragma unroll
        for (int i = 0; i < 8; i++)
            acur[i] = *(const float4*)(Arow + (size_t)i * HID + kb);

#pragma unroll
        for (int k4 = 0; k4 < 16; ++k4) {
            if (k4 < 15) {
#pragma unroll
                for (int i = 0; i < 8; i++)
                    anxt[i] = *(const float4*)(Arow + (size_t)i * HID + kb + (k4 + 1) * 4);
            }
            float4 b = *(const float4*)(&Bs[buf][e * 64 + ((k4 ^ (e & 15)) << 2)]);
#pragma unroll
            for (int i = 0; i < 8; i++) {
                acc[i] = fmaf(acur[i].x, b.x, acc[i]);
                acc[i] = fmaf(acur[i].y, b.y, acc[i]);
                acc[i] = fmaf(acur[i].z, b.z, acc[i]);
                acc[i] = fmaf(acur[i].w, b.w, acc[i]);
            }
#pragma unroll
            for (int i = 0; i < 8; i++) acur[i] = anxt[i];
        }

        if (c < 31) {
            const int nbuf = buf ^ 1;
            // writes go to nbuf (the buffer everyone finished reading last chunk),
            // reads this chunk were from buf -> single barrier after writes suffices
#pragma unroll
            for (int i = 0; i < 8; i++) {
                int f = i * 128 + tid; int es = f >> 4, k4 = f & 15;
                *(float4*)(&Bs[nbuf][es * 64 + ((k4 ^ (es & 15)) << 2)]) = wpre[i];
            }
            __syncthreads();
        }
    }

    // epilogue: logits + stable sigmoid (coalesced: 64 lanes = 64 consecutive experts)
#pragma unroll
    for (int i = 0; i < 8; i++) {
        int t = tok0 + i;
        float v = acc[i];
        out[(size_t)t * 64 + e] = v;
        float s;
        if (v >= 0.f) { s = 1.0f / (1.0f + expf(-v)); }
        else          { float ev = expf(v); s = ev / (1.0f + ev); }
        out[(size_t)T_TOKENS * 64 + (size_t)t * 64 + e] = s;
    }
}

// ---------------------------------------------------------------------------
// Kernel 2: persistent sinkhorn. 32 blocks x 256 threads = 1 token/thread.
// Cross-block sync via atomic RMWs only (coherence-point fresh): atomicAdd
// colsum partials -> threadfence -> atomicAdd counter; poll counter with
// atomicAdd(+0); gather colsums with atomicAdd(+0.0f).
// ---------------------------------------------------------------------------
__global__ __launch_bounds__(256, 1)
void sinkhorn_router_v2(const float* __restrict__ logits,
                        float* __restrict__ out_idx,
                        float* __restrict__ comm)
{
    __shared__ float tile[4][64 * 68];   // per-wave transpose tile (padded)
    __shared__ float d1_lds[64];
    __shared__ float pl[4][64];
    int* cnt = (int*)(comm + CNT_OFF);

    const int tid  = threadIdx.x;
    const int bid  = blockIdx.x;
    const int wave = tid >> 6, lane = tid & 63;
    const int t    = bid * 256 + tid;    // token id

    float c[64];
#pragma unroll
    for (int e4 = 0; e4 < 16; e4++) {
        float4 v = *(const float4*)(logits + (size_t)t * 64 + e4 * 4);
        c[e4 * 4 + 0] = expf(v.x);
        c[e4 * 4 + 1] = expf(v.y);
        c[e4 * 4 + 2] = expf(v.z);
        c[e4 * 4 + 3] = expf(v.w);
    }
    if (tid < 64) d1_lds[tid] = 1.0f;
    __syncthreads();

    float d0 = 0.f;
    float* tw = tile[wave];

    for (int iter = 0; iter < NITER; ++iter) {
        // ---- phase 1: d0[t] = (1/T) / (sum_e d1[e]*c[e] + eps)
        float s = 0.f;
#pragma unroll
        for (int e4 = 0; e4 < 16; e4++) {
            float4 dv = *(const float4*)(&d1_lds[e4 * 4]);
            s = fmaf(c[e4 * 4 + 0], dv.x, s);
            s = fmaf(c[e4 * 4 + 1], dv.y, s);
            s = fmaf(c[e4 * 4 + 2], dv.z, s);
            s = fmaf(c[e4 * 4 + 3], dv.w, s);
        }
        d0 = (1.0f / 8192.0f) / (s + 1e-8f);

        // ---- phase 2: block-local column sums of d0*c via per-wave LDS transpose
#pragma unroll
        for (int e4 = 0; e4 < 16; e4++) {
            float4 v;
            v.x = c[e4 * 4 + 0] * d0; v.y = c[e4 * 4 + 1] * d0;
            v.z = c[e4 * 4 + 2] * d0; v.w = c[e4 * 4 + 3] * d0;
            *(float4*)(&tw[lane * 68 + e4 * 4]) = v;
        }
        __syncthreads();
        float colsum = 0.f;
#pragma unroll 16
        for (int j = 0; j < 64; j++) colsum += tw[j * 68 + lane];
        pl[wave][lane] = colsum;
        __syncthreads();

        // ---- cross-block reduce via coherence-point atomics
        if (tid < 64) {
            float S = pl[0][tid] + pl[1][tid] + pl[2][tid] + pl[3][tid];
            atomicAdd(&comm[iter * 64 + tid], S);
            __threadfence();                       // order colsum adds before counter add
            if (tid == 0) {
                atomicAdd(&cnt[iter], 1);
                int g = 0;
                while (atomicAdd(&cnt[iter], 0) < SINK_BLOCKS && ++g < (1 << 26)) {
                    __builtin_amdgcn_s_sleep(1);
                }
            }
            // lanes reconverge here; values at coherence point are final once cnt==32
            float S2 = atomicAdd(&comm[iter * 64 + tid], 0.0f);
            d1_lds[tid] = (1.0f / 64.0f) / (S2 + 1e-8f);
        }
        __syncthreads();
    }

    // ---- argmax_e of sinkroute = d1[e]*c[e]*d0 (first max wins, like jnp.argmax)
    float best = -1.0f; int bi = 0;
#pragma unroll
    for (int e4 = 0; e4 < 16; e4++) {
        float4 dv = *(const float4*)(&d1_lds[e4 * 4]);
        float vv0 = (dv.x * c[e4 * 4 + 0]) * d0;
        float vv1 = (dv.y * c[e4 * 4 + 1]) * d0;
        float vv2 = (dv.z * c[e4 * 4 + 2]) * d0;
        float vv3 = (dv.w * c[e4 * 4 + 3]) * d0;
        if (vv0 > best) { best = vv0; bi = e4 * 4 + 0; }
        if (vv1 > best) { best = vv1; bi = e4 * 4 + 1; }
        if (vv2 > best) { best = vv2; bi = e4 * 4 + 2; }
        if (vv3 > best) { best = vv3; bi = e4 * 4 + 3; }
    }
    out_idx[t] = (float)bi;
}

extern "C" void kernel_launch(void* const* d_in, const int* in_sizes, int n_in,
                              void* d_out, int out_size, void* d_ws, size_t ws_size,
                              hipStream_t stream)
{
    (void)in_sizes; (void)n_in; (void)out_size; (void)ws_size;
    const float* hs = (const float*)d_in[0];   // (4,2048,2048) fp32 -> 8192 x 2048
    const float* W  = (const float*)d_in[1];   // (64,2048) fp32
    float* out      = (float*)d_out;           // [logits | affinities | index-as-float]
    float* comm     = (float*)d_ws;

    gemm_router_v2<<<512, 128, 0, stream>>>(hs, W, out, comm);
    sinkhorn_router_v2<<<SINK_BLOCKS, 256, 0, stream>>>(
        out, out + (size_t)2 * T_TOKENS * NEXP, comm);
}

// Round 3
// 249.125 us; speedup vs baseline: 3.9317x; 3.9317x over previous
//
#include <hip/hip_runtime.h>
#include <math.h>

#define T_TOKENS 8192
#define NEXP 64
#define HID 2048
#define NITER 30
#define SINK_BLOCKS 32
#define NCHUNK 32              // K-chunks of 64
#define QPC 512                // 16B-quads per chunk per W matrix (64 rows * 8 quads)
#define WREG 131072            // bf16 elements per W region (32*512*8)

typedef __bf16 bf16_t;
typedef bf16_t bf16x8 __attribute__((ext_vector_type(8)));
typedef bf16_t bf16x4 __attribute__((ext_vector_type(4)));
typedef float  f32x4  __attribute__((ext_vector_type(4)));

__device__ __forceinline__ void gload_lds16(const void* g, void* l) {
    __builtin_amdgcn_global_load_lds(
        (const __attribute__((address_space(1))) unsigned int*)g,
        (__attribute__((address_space(3))) unsigned int*)l, 16, 0, 0);
}

// ---------------------------------------------------------------------------
// Kernel 0: convert W (64x2048 f32) -> hi/lo bf16, quad-XOR-swizzled, laid out
// in the exact linear order the GEMM's global_load_lds consumes.
// Logical quad qi of row r stored at slot qi^(r&7); linear L = r*8 + slot.
// ---------------------------------------------------------------------------
__global__ __launch_bounds__(256)
void prep_whl(const float* __restrict__ W, bf16_t* __restrict__ wsw)
{
    int gid = blockIdx.x * 256 + threadIdx.x;   // 0..32767
    int region = gid >> 14;                     // 0 = hi, 1 = lo
    int qid = gid & 16383;
    int c = qid >> 9, L = qid & 511;
    int r = L >> 3, slot = L & 7;
    int qi = slot ^ (r & 7);
    const float* src = W + (size_t)r * HID + c * 64 + qi * 8;
    float4 v0 = *(const float4*)src;
    float4 v1 = *(const float4*)(src + 4);
    float x[8] = {v0.x, v0.y, v0.z, v0.w, v1.x, v1.y, v1.z, v1.w};
    bf16x8 q;
#pragma unroll
    for (int i = 0; i < 8; i++) {
        bf16_t h = (bf16_t)x[i];
        q[i] = (region == 0) ? h : (bf16_t)(x[i] - (float)h);
    }
    *(bf16x8*)(wsw + (size_t)region * WREG + (size_t)qid * 8) = q;
}

// ---------------------------------------------------------------------------
// Kernel 1: split-bf16 MFMA router GEMM. 512 blocks x 256 thr (4 waves).
// Block: 16 tokens x 64 experts x K=2048. Wave (s,nh): k32-half s, expert-half nh.
// 3-term split: C = Ah*Wh + Ah*Wl + Al*Wh  (error ~2^-18 relative, fp32-grade).
// A converted on the fly (read once per row); W staged via global_load_lds(16B).
// ---------------------------------------------------------------------------
__global__ __launch_bounds__(256, 2)
void gemm_mfma_split(const float* __restrict__ A, const bf16_t* __restrict__ Wq,
                     float* __restrict__ out)
{
    __shared__ bf16_t sA[2][2][16 * 64];    // [buf][h/l][row*64 + swz]
    __shared__ bf16_t sW[2][2][64 * 64];
    __shared__ float  red[2 * 512];         // k-merge scratch

    const int tid = threadIdx.x, lane = tid & 63, wv = tid >> 6;
    const int tok0 = blockIdx.x * 16;
    const int s = wv >> 1, nh = wv & 1;
    const int g = lane >> 4, m = lane & 15;

    f32x4 acc0 = {0.f, 0.f, 0.f, 0.f}, acc1 = {0.f, 0.f, 0.f, 0.f};

    // --- A staging map: thread -> (row ar, k4 group ak4)
    const int ar = tid >> 4, ak4 = tid & 15;
    const int a_woff = ar * 64 + (((ak4 >> 1) ^ (ar & 7)) << 3) + ((ak4 & 1) << 2);
    const float* ag = A + (size_t)(tok0 + ar) * HID + ak4 * 4;

    const bf16_t* whg = Wq;
    const bf16_t* wlg = Wq + WREG;

    // --- fragment read offsets (bf16 units)
    const int aq = s * 4 + g;
    const int a_roff  = m * 64 + ((aq ^ (m & 7)) << 3);
    const int n0 = nh * 32 + m, n1 = n0 + 16;
    const int b_roff0 = n0 * 64 + ((aq ^ (n0 & 7)) << 3);
    const int b_roff1 = n1 * 64 + ((aq ^ (n1 & 7)) << 3);

    // --- stage chunk 0 into buf 0
    {
        float4 av = *(const float4*)ag;
        float xs[4] = {av.x, av.y, av.z, av.w};
        bf16x4 hq, lq;
#pragma unroll
        for (int i = 0; i < 4; i++) {
            bf16_t h = (bf16_t)xs[i];
            hq[i] = h; lq[i] = (bf16_t)(xs[i] - (float)h);
        }
        *(bf16x4*)&sA[0][0][a_woff] = hq;
        *(bf16x4*)&sA[0][1][a_woff] = lq;
#pragma unroll
        for (int j = 0; j < 2; j++) {
            size_t q = (size_t)(j * 256 + wv * 64 + lane) * 8;
            gload_lds16(whg + q, &sW[0][0][(j * 256 + wv * 64) * 8]);
            gload_lds16(wlg + q, &sW[0][1][(j * 256 + wv * 64) * 8]);
        }
    }
    __syncthreads();

    for (int c = 0; c < NCHUNK; ++c) {
        const int buf = c & 1, nb = buf ^ 1;
        if (c + 1 < NCHUNK) {
            const int cn = c + 1;
            float4 av = *(const float4*)(ag + cn * 64);
#pragma unroll
            for (int j = 0; j < 2; j++) {
                size_t q = (size_t)(cn * QPC + j * 256 + wv * 64 + lane) * 8;
                gload_lds16(whg + q, &sW[nb][0][(j * 256 + wv * 64) * 8]);
                gload_lds16(wlg + q, &sW[nb][1][(j * 256 + wv * 64) * 8]);
            }
            float xs[4] = {av.x, av.y, av.z, av.w};
            bf16x4 hq, lq;
#pragma unroll
            for (int i = 0; i < 4; i++) {
                bf16_t h = (bf16_t)xs[i];
                hq[i] = h; lq[i] = (bf16_t)(xs[i] - (float)h);
            }
            *(bf16x4*)&sA[nb][0][a_woff] = hq;
            *(bf16x4*)&sA[nb][1][a_woff] = lq;
        }

        bf16x8 fAh  = *(const bf16x8*)&sA[buf][0][a_roff];
        bf16x8 fAl  = *(const bf16x8*)&sA[buf][1][a_roff];
        bf16x8 fWh0 = *(const bf16x8*)&sW[buf][0][b_roff0];
        bf16x8 fWl0 = *(const bf16x8*)&sW[buf][1][b_roff0];
        bf16x8 fWh1 = *(const bf16x8*)&sW[buf][0][b_roff1];
        bf16x8 fWl1 = *(const bf16x8*)&sW[buf][1][b_roff1];

        acc0 = __builtin_amdgcn_mfma_f32_16x16x32_bf16(fAh, fWh0, acc0, 0, 0, 0);
        acc0 = __builtin_amdgcn_mfma_f32_16x16x32_bf16(fAh, fWl0, acc0, 0, 0, 0);
        acc0 = __builtin_amdgcn_mfma_f32_16x16x32_bf16(fAl, fWh0, acc0, 0, 0, 0);
        acc1 = __builtin_amdgcn_mfma_f32_16x16x32_bf16(fAh, fWh1, acc1, 0, 0, 0);
        acc1 = __builtin_amdgcn_mfma_f32_16x16x32_bf16(fAh, fWl1, acc1, 0, 0, 0);
        acc1 = __builtin_amdgcn_mfma_f32_16x16x32_bf16(fAl, fWh1, acc1, 0, 0, 0);
        __syncthreads();
    }

    // --- merge k-halves: waves s=1 publish, waves s=0 reduce + epilogue
    if (s == 1) {
#pragma unroll
        for (int i = 0; i < 4; i++) {
            red[nh * 512 + lane * 8 + i]     = acc0[i];
            red[nh * 512 + lane * 8 + 4 + i] = acc1[i];
        }
    }
    __syncthreads();
    if (s == 0) {
        const int t0 = tok0 + (lane >> 4) * 4;
#pragma unroll
        for (int i = 0; i < 4; i++) {
            float v0 = acc0[i] + red[nh * 512 + lane * 8 + i];
            float v1 = acc1[i] + red[nh * 512 + lane * 8 + 4 + i];
            int t = t0 + i;
            out[(size_t)t * 64 + n0] = v0;
            out[(size_t)t * 64 + n1] = v1;
            float s0 = (v0 >= 0.f) ? 1.f / (1.f + expf(-v0))
                                   : expf(v0) / (1.f + expf(v0));
            float s1 = (v1 >= 0.f) ? 1.f / (1.f + expf(-v1))
                                   : expf(v1) / (1.f + expf(v1));
            out[(size_t)T_TOKENS * 64 + (size_t)t * 64 + n0] = s0;
            out[(size_t)T_TOKENS * 64 + (size_t)t * 64 + n1] = s1;
        }
    }
}

// ---------------------------------------------------------------------------
// Kernel 2: persistent sinkhorn, 32 blocks x 256 thr = 1 token/thread.
// Cross-block all-reduce: distinct slots part[iter][block][e], SYSTEM-scope
// store + SYSTEM-scope pipelined loads; value-signaling (0xAA poison < 0,
// partials strictly > 0). No fences, no RMW contention.
// ---------------------------------------------------------------------------
__global__ __launch_bounds__(256, 1)
void sinkhorn_v3(const float* __restrict__ logits,
                 float* __restrict__ out_idx,
                 float* __restrict__ part)
{
    __shared__ float tile[4][64 * 68];
    __shared__ float d1_lds[64];
    __shared__ float pl[4][64];
    const int tid = threadIdx.x;
    const int bid = blockIdx.x;
    const int wave = tid >> 6, lane = tid & 63;
    const int t = bid * 256 + tid;

    float c[64];
#pragma unroll
    for (int e4 = 0; e4 < 16; e4++) {
        float4 v = *(const float4*)(logits + (size_t)t * 64 + e4 * 4);
        c[e4 * 4 + 0] = expf(v.x);
        c[e4 * 4 + 1] = expf(v.y);
        c[e4 * 4 + 2] = expf(v.z);
        c[e4 * 4 + 3] = expf(v.w);
    }
    if (tid < 64) d1_lds[tid] = 1.0f;
    __syncthreads();

    float d0 = 0.f;
    float* tw = tile[wave];

    for (int iter = 0; iter < NITER; ++iter) {
        // phase 1: d0[t] = (1/T) / (sum_e d1[e]*c[e] + eps)
        float s = 0.f;
#pragma unroll
        for (int e4 = 0; e4 < 16; e4++) {
            float4 dv = *(const float4*)(&d1_lds[e4 * 4]);
            s = fmaf(c[e4 * 4 + 0], dv.x, s);
            s = fmaf(c[e4 * 4 + 1], dv.y, s);
            s = fmaf(c[e4 * 4 + 2], dv.z, s);
            s = fmaf(c[e4 * 4 + 3], dv.w, s);
        }
        d0 = (1.0f / 8192.0f) / (s + 1e-8f);

        // phase 2: block-local column sums via per-wave LDS transpose
#pragma unroll
        for (int e4 = 0; e4 < 16; e4++) {
            float4 v;
            v.x = c[e4 * 4 + 0] * d0; v.y = c[e4 * 4 + 1] * d0;
            v.z = c[e4 * 4 + 2] * d0; v.w = c[e4 * 4 + 3] * d0;
            *(float4*)(&tw[lane * 68 + e4 * 4]) = v;
        }
        __syncthreads();
        float colsum = 0.f;
#pragma unroll 16
        for (int j = 0; j < 64; j++) colsum += tw[j * 68 + lane];
        pl[wave][lane] = colsum;
        __syncthreads();

        // cross-block: publish own partial, gather all 32 (pipelined rounds)
        if (tid < 64) {
            float S = pl[0][tid] + pl[1][tid] + pl[2][tid] + pl[3][tid];
            __hip_atomic_store(&part[(size_t)(iter * SINK_BLOCKS + bid) * 64 + tid], S,
                               __ATOMIC_RELAXED, __HIP_MEMORY_SCOPE_SYSTEM);
            const float* pb = part + (size_t)iter * SINK_BLOCKS * 64 + tid;
            float v[SINK_BLOCKS];
            bool ok = false; int guard = 0;
            while (!ok && guard++ < (1 << 20)) {
                ok = true;
#pragma unroll
                for (int b = 0; b < SINK_BLOCKS; b++)
                    v[b] = __hip_atomic_load(pb + b * 64, __ATOMIC_RELAXED,
                                             __HIP_MEMORY_SCOPE_SYSTEM);
#pragma unroll
                for (int b = 0; b < SINK_BLOCKS; b++) ok = ok && (v[b] > 0.f);
            }
            float S2 = 0.f;
#pragma unroll
            for (int b = 0; b < SINK_BLOCKS; b++) S2 += v[b];
            d1_lds[tid] = (1.0f / 64.0f) / (S2 + 1e-8f);
        }
        __syncthreads();
    }

    // argmax_e of d1[e]*c[e]*d0 (first max wins)
    float best = -1.0f; int bi = 0;
#pragma unroll
    for (int e4 = 0; e4 < 16; e4++) {
        float4 dv = *(const float4*)(&d1_lds[e4 * 4]);
        float vv0 = (dv.x * c[e4 * 4 + 0]) * d0;
        float vv1 = (dv.y * c[e4 * 4 + 1]) * d0;
        float vv2 = (dv.z * c[e4 * 4 + 2]) * d0;
        float vv3 = (dv.w * c[e4 * 4 + 3]) * d0;
        if (vv0 > best) { best = vv0; bi = e4 * 4 + 0; }
        if (vv1 > best) { best = vv1; bi = e4 * 4 + 1; }
        if (vv2 > best) { best = vv2; bi = e4 * 4 + 2; }
        if (vv3 > best) { best = vv3; bi = e4 * 4 + 3; }
    }
    out_idx[t] = (float)bi;
}

extern "C" void kernel_launch(void* const* d_in, const int* in_sizes, int n_in,
                              void* d_out, int out_size, void* d_ws, size_t ws_size,
                              hipStream_t stream)
{
    (void)in_sizes; (void)n_in; (void)out_size; (void)ws_size;
    const float* hs = (const float*)d_in[0];     // 8192 x 2048 f32
    const float* W  = (const float*)d_in[1];     // 64 x 2048 f32
    float* out      = (float*)d_out;             // [logits | affinities | idx]
    bf16_t* wsw     = (bf16_t*)d_ws;             // 512 KB: Wh | Wl (swizzled)
    float* part     = (float*)d_ws + WREG;       // +512 KB: 30*32*64 slots

    prep_whl<<<128, 256, 0, stream>>>(W, wsw);
    gemm_mfma_split<<<512, 256, 0, stream>>>(hs, wsw, out);
    sinkhorn_v3<<<SINK_BLOCKS, 256, 0, stream>>>(
        out, out + (size_t)2 * T_TOKENS * NEXP, part);
}

// Round 4
// 220.333 us; speedup vs baseline: 4.4455x; 1.1307x over previous
//
#include <hip/hip_runtime.h>
#include <math.h>

#define T_TOKENS 8192
#define NEXP 64
#define HID 2048
#define NITER 30
#define SINK_BLOCKS 32
#define WREG 131072          // bf16 elements per W region (64 x 2048)

typedef __bf16 bf16_t;
typedef bf16_t bf16x8 __attribute__((ext_vector_type(8)));
typedef float  f32x4  __attribute__((ext_vector_type(4)));

__device__ __forceinline__ void gload_lds16(const void* g, void* l) {
    __builtin_amdgcn_global_load_lds(
        (const __attribute__((address_space(1))) unsigned int*)g,
        (__attribute__((address_space(3))) unsigned int*)l, 16, 0, 0);
}

// ---------------------------------------------------------------------------
// Kernel 0: W (64x2048 f32) -> hi/lo bf16, per-64k-chunk quad-XOR-swizzled,
// linear in the exact order gemm's global_load_lds consumes.
// chunk c (0..31), row r, slot s holds quad q = s ^ (r&7) of W[r][c*64..].
// ---------------------------------------------------------------------------
__global__ __launch_bounds__(256)
void prep_whl(const float* __restrict__ W, bf16_t* __restrict__ wsw)
{
    int gid = blockIdx.x * 256 + threadIdx.x;   // 0..32767
    int region = gid >> 14;                     // 0 = hi, 1 = lo
    int qid = gid & 16383;
    int c = qid >> 9, L = qid & 511;
    int r = L >> 3, slot = L & 7;
    int qi = slot ^ (r & 7);
    const float* src = W + (size_t)r * HID + c * 64 + qi * 8;
    float4 v0 = *(const float4*)src;
    float4 v1 = *(const float4*)(src + 4);
    float x[8] = {v0.x, v0.y, v0.z, v0.w, v1.x, v1.y, v1.z, v1.w};
    bf16x8 q;
#pragma unroll
    for (int i = 0; i < 8; i++) {
        bf16_t h = (bf16_t)x[i];
        q[i] = (region == 0) ? h : (bf16_t)(x[i] - (float)h);
    }
    *(bf16x8*)(wsw + (size_t)region * WREG + (size_t)qid * 8) = q;
}

// ---------------------------------------------------------------------------
// Kernel 1: split-K(2) MFMA GEMM. 512 blocks x 256 thr (4 waves).
// Block: 32 tokens x 64 experts x K-half 1024 (16 chunks of 64).
// ALL staging via global_load_lds(16B): A raw f32 (source-address swizzled),
// W prepped bf16. Wave (mgrp,ngrp) = 16 tok x 32 exp; 3-term split-bf16 MFMA.
// Accumulators live whole-kernel; plain-store epilogue to part[ks][t][e].
// ---------------------------------------------------------------------------
__global__ __launch_bounds__(256, 2)
void gemm_splitk(const float* __restrict__ A, const bf16_t* __restrict__ Wq,
                 float* __restrict__ part)
{
    __shared__ float  sA[2][32 * 64];       // 8 KB x2 (raw f32, swizzled chunks)
    __shared__ bf16_t sW[2][2][64 * 64];    // 8 KB x4 (hi/lo bf16, swizzled)

    const int tid = threadIdx.x, lane = tid & 63, wv = tid >> 6;
    const int ks   = blockIdx.x & 1;
    const int tok0 = (blockIdx.x >> 1) * 32;
    const int mgrp = wv >> 1, ngrp = wv & 1;
    const int g = lane >> 4, m = lane & 15;
    const int arow = mgrp * 16 + m;
    const int m7 = m & 7;

    f32x4 acc0 = {0.f, 0.f, 0.f, 0.f}, acc1 = {0.f, 0.f, 0.f, 0.f};

    // staging maps (2 A-instrs + 4 W-instrs per wave per chunk)
    int ap[2], acs[2];   // A: lds position block, swizzled source chunk
#pragma unroll
    for (int j = 0; j < 2; j++) {
        int p = (wv * 2 + j) * 64 + lane;          // 16B-position 0..511
        ap[j] = p;
        int r = p >> 4, slot = p & 15;
        acs[j] = slot ^ (r & 7);                   // source 16B-chunk within row
    }

#define STAGE_CHUNK(cc, dst)                                                    \
    {                                                                           \
        const int _cc = (cc);                                                   \
        _Pragma("unroll")                                                       \
        for (int j = 0; j < 2; j++) {                                           \
            int r = ap[j] >> 4;                                                 \
            const float* src = A + (size_t)(tok0 + r) * HID + ks * 1024         \
                             + _cc * 64 + acs[j] * 4;                           \
            gload_lds16(src, &sA[dst][(wv * 2 + j) * 256]);                     \
        }                                                                       \
        const size_t chb = ((size_t)(ks * 16 + _cc) * 512) * 8;                 \
        _Pragma("unroll")                                                       \
        for (int j = 0; j < 2; j++) {                                           \
            size_t q8 = chb + (size_t)((wv * 2 + j) * 64 + lane) * 8;           \
            gload_lds16(Wq + q8,        &sW[dst][0][(wv * 2 + j) * 512]);       \
            gload_lds16(Wq + WREG + q8, &sW[dst][1][(wv * 2 + j) * 512]);       \
        }                                                                       \
    }

    STAGE_CHUNK(0, 0);
    __syncthreads();

    for (int cc = 0; cc < 16; ++cc) {
        const int buf = cc & 1, nb = buf ^ 1;
        if (cc + 1 < 16) STAGE_CHUNK(cc + 1, nb);

        const float*  sAc = sA[buf];
        const bf16_t* sWh = sW[buf][0];
        const bf16_t* sWl = sW[buf][1];
#pragma unroll
        for (int k32 = 0; k32 < 2; ++k32) {
            int s0 = (k32 * 8 + g * 2) ^ m7;
            float4 x0 = *(const float4*)&sAc[arow * 64 + s0 * 4];
            float4 x1 = *(const float4*)&sAc[arow * 64 + (s0 ^ 1) * 4];
            float xs[8] = {x0.x, x0.y, x0.z, x0.w, x1.x, x1.y, x1.z, x1.w};
            bf16x8 fAh, fAl;
#pragma unroll
            for (int i = 0; i < 8; i++) {
                bf16_t h = (bf16_t)xs[i];
                fAh[i] = h; fAl[i] = (bf16_t)(xs[i] - (float)h);
            }
            const int q = k32 * 4 + g;
            {
                int off = (ngrp * 32 + m) * 64 + (q ^ m7) * 8;
                bf16x8 fWh = *(const bf16x8*)&sWh[off];
                bf16x8 fWl = *(const bf16x8*)&sWl[off];
                acc0 = __builtin_amdgcn_mfma_f32_16x16x32_bf16(fAh, fWh, acc0, 0, 0, 0);
                acc0 = __builtin_amdgcn_mfma_f32_16x16x32_bf16(fAh, fWl, acc0, 0, 0, 0);
                acc0 = __builtin_amdgcn_mfma_f32_16x16x32_bf16(fAl, fWh, acc0, 0, 0, 0);
            }
            {
                int off = (ngrp * 32 + 16 + m) * 64 + (q ^ m7) * 8;
                bf16x8 fWh = *(const bf16x8*)&sWh[off];
                bf16x8 fWl = *(const bf16x8*)&sWl[off];
                acc1 = __builtin_amdgcn_mfma_f32_16x16x32_bf16(fAh, fWh, acc1, 0, 0, 0);
                acc1 = __builtin_amdgcn_mfma_f32_16x16x32_bf16(fAh, fWl, acc1, 0, 0, 0);
                acc1 = __builtin_amdgcn_mfma_f32_16x16x32_bf16(fAl, fWh, acc1, 0, 0, 0);
            }
        }
        __syncthreads();
    }

    float* pb = part + (size_t)ks * T_TOKENS * 64;
#pragma unroll
    for (int i = 0; i < 4; i++) {
        int t = tok0 + mgrp * 16 + g * 4 + i;     // C: row=(lane>>4)*4+reg
        pb[(size_t)t * 64 + ngrp * 32 + m]      = acc0[i];   // col=lane&15
        pb[(size_t)t * 64 + ngrp * 32 + 16 + m] = acc1[i];
    }
#undef STAGE_CHUNK
}

// ---------------------------------------------------------------------------
// Kernel 2: persistent sinkhorn, 32 blocks x 256 thr = 1 token/thread.
// Load phase fuses the split-K reduce + logits + sigmoid stores.
// Cross-block sync: publish 64 partials (relaxed-agent) -> release fence ->
// ONE flag store; readers poll 1 flag/lane (32 loads/round, 64x less traffic
// than r3's data-poll), then gather data once. Flags value-signal off 0xAA
// poison (<0).
// ---------------------------------------------------------------------------
__global__ __launch_bounds__(256, 1)
void sinkhorn_v4(const float* __restrict__ part,
                 float* __restrict__ out,
                 float* __restrict__ sd,      // 30*32*64 partial slots
                 float* __restrict__ fl)      // 30*32 flags
{
    __shared__ float tile[4][64 * 68];
    __shared__ float d1_lds[64];
    __shared__ float pl[4][64];
    const int tid = threadIdx.x, bid = blockIdx.x;
    const int wave = tid >> 6, lane = tid & 63;
    const int t = bid * 256 + tid;

    float* logits = out;
    float* aff    = out + (size_t)T_TOKENS * 64;
    float* idx    = out + (size_t)2 * T_TOKENS * 64;

    const float* p0 = part + (size_t)t * 64;
    const float* p1 = part + (size_t)T_TOKENS * 64 + (size_t)t * 64;

    float c[64];
#pragma unroll
    for (int e4 = 0; e4 < 16; e4++) {
        float4 a = *(const float4*)(p0 + e4 * 4);
        float4 b = *(const float4*)(p1 + e4 * 4);
        float4 v = {a.x + b.x, a.y + b.y, a.z + b.z, a.w + b.w};
        *(float4*)(logits + (size_t)t * 64 + e4 * 4) = v;
        float4 sg;
        sg.x = (v.x >= 0.f) ? 1.f / (1.f + expf(-v.x)) : expf(v.x) / (1.f + expf(v.x));
        sg.y = (v.y >= 0.f) ? 1.f / (1.f + expf(-v.y)) : expf(v.y) / (1.f + expf(v.y));
        sg.z = (v.z >= 0.f) ? 1.f / (1.f + expf(-v.z)) : expf(v.z) / (1.f + expf(v.z));
        sg.w = (v.w >= 0.f) ? 1.f / (1.f + expf(-v.w)) : expf(v.w) / (1.f + expf(v.w));
        *(float4*)(aff + (size_t)t * 64 + e4 * 4) = sg;
        c[e4 * 4 + 0] = expf(v.x);
        c[e4 * 4 + 1] = expf(v.y);
        c[e4 * 4 + 2] = expf(v.z);
        c[e4 * 4 + 3] = expf(v.w);
    }
    if (tid < 64) d1_lds[tid] = 1.0f;
    __syncthreads();

    float d0 = 0.f;
    float* tw = tile[wave];

    for (int iter = 0; iter < NITER; ++iter) {
        // phase 1: d0[t] = (1/T) / (sum_e d1[e]*c[e] + eps)
        float s = 0.f;
#pragma unroll
        for (int e4 = 0; e4 < 16; e4++) {
            float4 dv = *(const float4*)(&d1_lds[e4 * 4]);
            s = fmaf(c[e4 * 4 + 0], dv.x, s);
            s = fmaf(c[e4 * 4 + 1], dv.y, s);
            s = fmaf(c[e4 * 4 + 2], dv.z, s);
            s = fmaf(c[e4 * 4 + 3], dv.w, s);
        }
        d0 = (1.0f / 8192.0f) / (s + 1e-8f);

        // phase 2: block-local column sums via per-wave LDS transpose
#pragma unroll
        for (int e4 = 0; e4 < 16; e4++) {
            float4 v;
            v.x = c[e4 * 4 + 0] * d0; v.y = c[e4 * 4 + 1] * d0;
            v.z = c[e4 * 4 + 2] * d0; v.w = c[e4 * 4 + 3] * d0;
            *(float4*)(&tw[lane * 68 + e4 * 4]) = v;
        }
        __syncthreads();
        float colsum = 0.f;
#pragma unroll 16
        for (int j = 0; j < 64; j++) colsum += tw[j * 68 + lane];
        pl[wave][lane] = colsum;
        __syncthreads();

        // cross-block: publish partial + flag; poll flags; gather once
        if (tid < 64) {
            float S = pl[0][tid] + pl[1][tid] + pl[2][tid] + pl[3][tid];
            __hip_atomic_store(&sd[(size_t)(iter * SINK_BLOCKS + bid) * 64 + tid], S,
                               __ATOMIC_RELAXED, __HIP_MEMORY_SCOPE_AGENT);
            if (tid == 0) {
                __builtin_amdgcn_fence(__ATOMIC_RELEASE, "agent");
                __hip_atomic_store(&fl[iter * SINK_BLOCKS + bid], 1.0f,
                                   __ATOMIC_RELAXED, __HIP_MEMORY_SCOPE_AGENT);
            }
            if (tid < SINK_BLOCKS) {
                int guard = 0;
                for (;;) {
                    float f = __hip_atomic_load(&fl[iter * SINK_BLOCKS + tid],
                                                __ATOMIC_RELAXED, __HIP_MEMORY_SCOPE_AGENT);
                    if (f > 0.f || ++guard >= (1 << 20)) break;
                    __builtin_amdgcn_s_sleep(1);
                }
            }
            const float* base = sd + (size_t)iter * SINK_BLOCKS * 64 + tid;
            float v[SINK_BLOCKS];
#pragma unroll
            for (int b = 0; b < SINK_BLOCKS; b++)
                v[b] = __hip_atomic_load(base + b * 64, __ATOMIC_RELAXED,
                                         __HIP_MEMORY_SCOPE_AGENT);
            float S2 = 0.f;
#pragma unroll
            for (int b = 0; b < SINK_BLOCKS; b++) S2 += v[b];
            d1_lds[tid] = (1.0f / 64.0f) / (S2 + 1e-8f);
        }
        __syncthreads();
    }

    // argmax_e of d1[e]*c[e]*d0 (first max wins, like jnp.argmax)
    float best = -1.0f; int bi = 0;
#pragma unroll
    for (int e4 = 0; e4 < 16; e4++) {
        float4 dv = *(const float4*)(&d1_lds[e4 * 4]);
        float vv0 = (dv.x * c[e4 * 4 + 0]) * d0;
        float vv1 = (dv.y * c[e4 * 4 + 1]) * d0;
        float vv2 = (dv.z * c[e4 * 4 + 2]) * d0;
        float vv3 = (dv.w * c[e4 * 4 + 3]) * d0;
        if (vv0 > best) { best = vv0; bi = e4 * 4 + 0; }
        if (vv1 > best) { best = vv1; bi = e4 * 4 + 1; }
        if (vv2 > best) { best = vv2; bi = e4 * 4 + 2; }
        if (vv3 > best) { best = vv3; bi = e4 * 4 + 3; }
    }
    idx[t] = (float)bi;
}

extern "C" void kernel_launch(void* const* d_in, const int* in_sizes, int n_in,
                              void* d_out, int out_size, void* d_ws, size_t ws_size,
                              hipStream_t stream)
{
    (void)in_sizes; (void)n_in; (void)out_size; (void)ws_size;
    const float* hs = (const float*)d_in[0];   // 8192 x 2048 f32
    const float* W  = (const float*)d_in[1];   // 64 x 2048 f32
    float* out      = (float*)d_out;           // [logits | affinities | idx]

    bf16_t* wsw = (bf16_t*)d_ws;               // 512 KB prepped W (hi|lo)
    float*  part = (float*)d_ws + 131072;      // 4 MB: part[2][8192][64]
    float*  sd   = part + 2 * T_TOKENS * 64;   // 240 KB sink partial slots
    float*  fl   = sd + NITER * SINK_BLOCKS * 64;  // flags

    prep_whl<<<128, 256, 0, stream>>>(W, wsw);
    gemm_splitk<<<512, 256, 0, stream>>>(hs, wsw, part);
    sinkhorn_v4<<<SINK_BLOCKS, 256, 0, stream>>>(part, out, sd, fl);
}